// Round 5
// baseline (225.577 us; speedup 1.0000x reference)
//
#include <hip/hip_runtime.h>
#include <hip/hip_bf16.h>

// y_i = x_i^T Q x_i + b^T x_i + c ; N=16384, D=1024, fp32.
// Round 9: barrier-free rounds. R8 post-mortem: 3450 cyc/round vs ~700 cyc
// of issue work -> 75% stall from per-round __syncthreads (implicit
// vmcnt(0) drains the Q prefetch inside every round; 2 barrier-locked
// waves/SIMD can't hide it). Restructure:
//  - 8 waves own DISJOINT K-eighths (128 k) of all 64 rows; A = 64 AGPR.
//    Disjoint slices -> Q needs NO LDS and NO cross-wave sync.
//  - pass-1 kernel converts Q fp32->bf16 into d_ws (2 MB, L2-resident);
//    main kernel loads B-frags DIRECT to registers: 1 global_dwordx4 ==
//    one 16x16x32 B-frag (k fast axis via x^TQx == x^TQ^Tx, as R8).
//    Per-round: 4 loads + 16 MFMA + 16 FMA. bA/bB reg dbuf, unroll-2.
//  - barriers ONLY at 8 xv phase boundaries (wave p dumps phase-p x
//    values from its A-frags as f32; cvt once, not per round).
//  - L2 delivery floor: 32 KB/CU/round ~ 585 cyc -> ~16 us + prologue.
// Regs ~80 VGPR + 64 AGPR = ~144 unified @ (512,2), no spill risk.
// xv LDS stride 132 f32: read 2-way (free), dump once. Direct y stores.

#define DD 1024
#define XSTRIDE 132            // xv row stride in floats (128 + 4)
#define XPHASE (64 * XSTRIDE)  // floats per xv phase buffer

typedef short v8s __attribute__((ext_vector_type(8)));
typedef float v4f __attribute__((ext_vector_type(4)));

__device__ __forceinline__ short f2b(float f) {
    union { __hip_bfloat16 h; short s; } u;
    u.h = __float2bfloat16(f);
    return u.s;
}
__device__ __forceinline__ float b2f(short s) {
    union { unsigned u; float f; } uu;
    uu.u = ((unsigned)(unsigned short)s) << 16;
    return uu.f;
}

__global__ __launch_bounds__(256, 4)
void cvt_kernel(const float* __restrict__ Q, short* __restrict__ qb)
{
    const int idx = (blockIdx.x * 256 + threadIdx.x) * 4;
    const float4 f = *(const float4*)(Q + idx);
    short4 s4;
    s4.x = f2b(f.x); s4.y = f2b(f.y); s4.z = f2b(f.z); s4.w = f2b(f.w);
    *(short4*)(qb + idx) = s4;
}

#define MFMA16(A, B, C) __builtin_amdgcn_mfma_f32_16x16x32_bf16(A, B, C, 0, 0, 0)

// wave `wave` dumps its A-frags (x[64 rows][wave's 128 k] == phase-`wave`
// columns) as f32 into xvb[wave&1]. Called only by one wave, post-barrier.
#define DUMP_XV()                                                         \
  { _Pragma("unroll")                                                     \
    for (int g = 0; g < 4; ++g) {                                         \
      _Pragma("unroll")                                                   \
      for (int s = 0; s < 4; ++s) {                                       \
        float* d = &xvb[wave & 1][(g * 16 + l15) * XSTRIDE + s * 32 + quad * 8]; \
        const v8s fr = a[g][s];                                           \
        float4 lo, hi;                                                    \
        lo.x = b2f(fr[0]); lo.y = b2f(fr[1]); lo.z = b2f(fr[2]); lo.w = b2f(fr[3]); \
        hi.x = b2f(fr[4]); hi.y = b2f(fr[5]); hi.z = b2f(fr[6]); hi.w = b2f(fr[7]); \
        *(float4*)d = lo; *((float4*)d + 1) = hi;                         \
      } } }

// one 16-col round: 16 MFMA on B regs BR, then distributed dot with xv.
#define ROUND(BR, T)                                                      \
  { v4f cf0 = (v4f){0,0,0,0}, cf1 = (v4f){0,0,0,0};                       \
    v4f cf2 = (v4f){0,0,0,0}, cf3 = (v4f){0,0,0,0};                       \
    _Pragma("unroll")                                                     \
    for (int s = 0; s < 4; ++s) {                                         \
      cf0 = MFMA16(a[0][s], BR[s], cf0);                                  \
      cf1 = MFMA16(a[1][s], BR[s], cf1);                                  \
      cf2 = MFMA16(a[2][s], BR[s], cf2);                                  \
      cf3 = MFMA16(a[3][s], BR[s], cf3);                                  \
    }                                                                     \
    const float* xp = xq + ((((T) >> 3) & 1) * XPHASE) + (((T) & 7) * 16); \
    const float bb = (wave == 0) ? bvec[(T) * 16 + l15] : 0.f;            \
    _Pragma("unroll")                                                     \
    for (int g = 0; g < 4; ++g) {                                         \
      const v4f cfg = (g == 0) ? cf0 : ((g == 1) ? cf1 : ((g == 2) ? cf2 : cf3)); \
      _Pragma("unroll")                                                   \
      for (int r = 0; r < 4; ++r) {                                       \
        const float xv = xp[(g * 16 + r) * XSTRIDE];                      \
        acc[g][r] += cfg[r] * xv;                                         \
        if (wave == 0) acc[g][r] += bb * xv;                              \
      } } }

__global__ __launch_bounds__(512, 2)
void quad_kernel(const float* __restrict__ x, const short* __restrict__ qb,
                 const float* __restrict__ bvec, const float* __restrict__ cptr,
                 float* __restrict__ y)
{
    __shared__ __align__(16) float xvb[2][XPHASE];   // 67.6 KB: x cols, f32
    __shared__ float yred[8][64];                    //  2.0 KB

    const int tid  = threadIdx.x;
    const int lane = tid & 63;
    const int wave = tid >> 6;       // 0..7: owns K-eighth [wave*128, +128)
    const int quad = lane >> 4;
    const int l15  = lane & 15;

    const int row_base = blockIdx.x * 64;
    const int kb = wave * 128;

    // ---- B round-0 loads first (in flight under the whole A prologue) ----
    // B-frag (16x16x32): n = l15, k = quad*8 + j  -> one dwordx4 per kstep.
    const short* qp = qb + (size_t)l15 * DD + kb + quad * 8;
    v8s bA[4], bB[4];
    #pragma unroll
    for (int s = 0; s < 4; ++s) bA[s] = *(const v8s*)(qp + s * 32);

    // ---- A prologue: x[64 rows][wave's 128 k] -> 16 bf16 v8s in AGPRs ----
    // A-frag: m = l15, k = quad*8 + j
    v8s a[4][4];
    #pragma unroll
    for (int g = 0; g < 4; ++g) {
        const float* xr = x + (size_t)(row_base + g * 16 + l15) * DD + kb + quad * 8;
        #pragma unroll
        for (int s = 0; s < 4; ++s) {
            const float4 f0 = *(const float4*)(xr + s * 32);
            const float4 f1 = *(const float4*)(xr + s * 32 + 4);
            v8s t;
            t[0]=f2b(f0.x); t[1]=f2b(f0.y); t[2]=f2b(f0.z); t[3]=f2b(f0.w);
            t[4]=f2b(f1.x); t[5]=f2b(f1.y); t[6]=f2b(f1.z); t[7]=f2b(f1.w);
            a[g][s] = t;
            asm volatile("" : "+a"(a[g][s]));   // steer to AGPR
        }
    }

    // phase-0 xv dump by wave 0, made visible by B_0
    if (wave == 0) DUMP_XV();
    __syncthreads();   // B_0 (the only barrier besides 7 phase + 1 final)

    float acc[4][4];
    #pragma unroll
    for (int g = 0; g < 4; ++g)
        #pragma unroll
        for (int r = 0; r < 4; ++r) acc[g][r] = 0.f;

    // xv read base: row = g*16 + quad*4 + r, col = (t&7)*16 + l15
    const float* xq = &xvb[0][0] + quad * 4 * XSTRIDE + l15;

    for (int t = 0; t < 64; t += 2) {
        if ((t & 7) == 0) {
            if (t) __syncthreads();                 // B_p: phase p = t>>3
            if (wave == (t >> 3) + 1) DUMP_XV();    // dump phase p+1 (p+1<=7)
        }
        // even round t: issue loads for t+1, compute with bA
        qp += 16 * DD;
        #pragma unroll
        for (int s = 0; s < 4; ++s) bB[s] = *(const v8s*)(qp + s * 32);
        ROUND(bA, t);
        // odd round t+1: issue loads for t+2, compute with bB
        qp += 16 * DD;
        if (t + 2 < 64) {
            #pragma unroll
            for (int s = 0; s < 4; ++s) bA[s] = *(const v8s*)(qp + s * 32);
        }
        ROUND(bB, t + 1);
    }

    // ---- reduce 16 l15-lanes (shfl), then 8 waves (LDS), direct store ----
    #pragma unroll
    for (int g = 0; g < 4; ++g)
        #pragma unroll
        for (int r = 0; r < 4; ++r) {
            float v = acc[g][r];
            v += __shfl_xor(v, 1); v += __shfl_xor(v, 2);
            v += __shfl_xor(v, 4); v += __shfl_xor(v, 8);
            if (l15 == 0)
                yred[wave][g * 16 + quad * 4 + r] = v;
        }
    __syncthreads();
    if (tid < 64) {
        float s = yred[0][tid] + yred[1][tid] + yred[2][tid] + yred[3][tid]
                + yred[4][tid] + yred[5][tid] + yred[6][tid] + yred[7][tid];
        y[row_base + tid] = s + cptr[0];
    }
}

extern "C" void kernel_launch(void* const* d_in, const int* in_sizes, int n_in,
                              void* d_out, int out_size, void* d_ws, size_t ws_size,
                              hipStream_t stream)
{
    const float* x = (const float*)d_in[0];
    const float* Q = (const float*)d_in[1];
    const float* b = (const float*)d_in[2];
    const float* c = (const float*)d_in[3];
    float* y = (float*)d_out;
    short* qb = (short*)d_ws;   // 2 MB bf16 copy of Q

    // pass 1: Q fp32 -> bf16 (1M elems, 1024 blocks x 256 thr x float4)
    cvt_kernel<<<dim3(1024), dim3(256), 0, stream>>>(Q, qb);
    // pass 2: full-K blocks own rows exclusively -> direct stores, no memset
    quad_kernel<<<dim3(256), dim3(512), 0, stream>>>(x, qb, b, c, y);
}

// Round 6
// 160.190 us; speedup vs baseline: 1.4082x; 1.4082x over previous
//
#include <hip/hip_runtime.h>
#include <hip/hip_bf16.h>

// y_i = x_i^T Q x_i + b^T x_i + c ; N=16384, D=1024, fp32.
// Round 10: R8 structure + DMA staging + counted-vmcnt barriers.
// R9 post-mortem: WRITE_SIZE 104MB = scratch spill (a[4][4]+bA/bB blew
// the 128-VGPR cap the compiler enforced) -> back to R8's proven reg
// shape (a[2][8], 64 AGPR, VGPR ~92, WRITE 64KB). R8's stall anatomy:
// ~2700 cyc/round = staging VALU (32 f2b + 8 ds_write/thread, VALUBusy
// 23%) + __syncthreads vmcnt(0) drain vs L2 burst (64KB fp32/CU/round).
// Fixes:
//  - cvt pass writes Q as bf16, PRE-TILED (64 tiles of 16 rows x 2048B)
//    and PRE-SWIZZLED (byte 2k ^ ((row&7)<<4)) into d_ws (2MB, R9-proven
//    size). Main kernel stages a tile with 4x global_load_lds(16B)/thread:
//    zero staging VGPRs, zero f2b in main loop, L2 bytes/round halved.
//  - xv phases 128 cols (34.8KB dbuf) -> LDS fits THREE 32KB tile bufs;
//    round t issues tile t+2; end-of-round = s_waitcnt vmcnt(4) +
//    s_barrier (T4): tile t+2's loads stay in flight ACROSS the barrier,
//    ~2 rounds of latency cover. lgkmcnt(0) covers xv-dump visibility.
//  - all register-array indices compile-time (R9 lesson / rule 20).
// 8 waves = 4 kq x 2 rg own disjoint (k-quarter, 32-row) slices; dot is
// distributed (each wave dots its own kq-partial); full-K blocks ->
// direct y stores, no atomics/memset. Grid 256 = 1 block/CU.

#define DD 1024
#define TILEB 32768          // bytes per staged Q tile (16 rows x 2048 B)
#define XROWS 136            // xv row stride in shorts (128 + 8 pad)
#define XPH (64 * XROWS)     // shorts per xv phase buffer

typedef short v8s __attribute__((ext_vector_type(8)));
typedef float v4f __attribute__((ext_vector_type(4)));

__device__ __forceinline__ short f2b(float f) {
    union { __hip_bfloat16 h; short s; } u;
    u.h = __float2bfloat16(f);
    return u.s;
}
__device__ __forceinline__ float b2f(short s) {
    union { unsigned u; float f; } uu;
    uu.u = ((unsigned)(unsigned short)s) << 16;
    return uu.f;
}

#define MFMA16(A, B, C) __builtin_amdgcn_mfma_f32_16x16x32_bf16(A, B, C, 0, 0, 0)

// pass 1: Q fp32 -> bf16, tiled+swizzled LDS image in d_ws.
// element k of Q-row n lands at tile (n>>4), row (n&15),
// row-byte (2k) ^ ((n&7)<<4).
__global__ __launch_bounds__(256, 4)
void cvt_kernel(const float* __restrict__ Q, char* __restrict__ qb)
{
    const int gid = blockIdx.x * 256 + threadIdx.x;   // 131072 threads
    const int n  = gid >> 7;          // Q row 0..1023
    const int k0 = (gid & 127) * 8;   // 8 k's per thread
    const float4 f0 = *(const float4*)(Q + (size_t)n * DD + k0);
    const float4 f1 = *(const float4*)(Q + (size_t)n * DD + k0 + 4);
    v8s t;
    t[0]=f2b(f0.x); t[1]=f2b(f0.y); t[2]=f2b(f0.z); t[3]=f2b(f0.w);
    t[4]=f2b(f1.x); t[5]=f2b(f1.y); t[6]=f2b(f1.z); t[7]=f2b(f1.w);
    char* dst = qb + (size_t)(n >> 4) * TILEB + (size_t)(n & 15) * 2048
              + (((unsigned)(k0 * 2)) ^ (((unsigned)n & 7u) << 4));
    *(v8s*)dst = t;
}

__global__ __launch_bounds__(512, 2)
void quad_kernel(const float* __restrict__ x, const char* __restrict__ qb,
                 const float* __restrict__ bvec, const float* __restrict__ cptr,
                 float* __restrict__ y)
{
    __shared__ __align__(1024) char tile[3][TILEB];   // 96 KB, triple buffer
    __shared__ __align__(16) short xvb[2][XPH];       // 34 KB, phase dbuf
    __shared__ float yred[4][64];                     //  1 KB

    const int tid  = threadIdx.x;
    const int lane = tid & 63;
    const int wave = tid >> 6;       // 0..7
    const int quad = lane >> 4;
    const int l15  = lane & 15;
    const int kq   = wave & 3;       // K quarter this wave owns
    const int rg   = wave >> 2;      // row group 0..1 (32 rows each)

    const int row_base = blockIdx.x * 64;
    const int xorc = (l15 & 7) << 4;

    // stage tile t into buffer buf: 4 x global_load_lds(16B) per thread.
    // LDS dest is linear (base + i*8192 + tid*16) == qb's byte layout.
    auto stage = [&](int buf, int t) {
        const char* gp = qb + (size_t)t * TILEB + tid * 16;
        char* lp = &tile[buf][0] + tid * 16;
        #pragma unroll
        for (int i = 0; i < 4; ++i)
            __builtin_amdgcn_global_load_lds(
                (const __attribute__((address_space(1))) unsigned int*)(gp + i * 8192),
                (__attribute__((address_space(3))) unsigned int*)(lp + i * 8192),
                16, 0, 0);
    };

    // ---- prologue: tiles 0,1 in flight, then A-load (HBM-bound) ----
    stage(0, 0);
    stage(1, 1);

    // A = x[rg's 32 rows][kq*256 ..+256) bf16 frags: a[2][8] = 64 AGPR.
    // A-frag (16x16x32): m = l15, k = quad*8 + j.
    v8s a[2][8];
    #pragma unroll
    for (int g = 0; g < 2; ++g) {
        const float* xr = x + (size_t)(row_base + rg * 32 + g * 16 + l15) * DD
                        + kq * 256 + quad * 8;
        #pragma unroll
        for (int s = 0; s < 8; ++s) {
            const float4 f0 = *(const float4*)(xr + s * 32);
            const float4 f1 = *(const float4*)(xr + s * 32 + 4);
            v8s t;
            t[0]=f2b(f0.x); t[1]=f2b(f0.y); t[2]=f2b(f0.z); t[3]=f2b(f0.w);
            t[4]=f2b(f1.x); t[5]=f2b(f1.y); t[6]=f2b(f1.z); t[7]=f2b(f1.w);
            a[g][s] = t;
            asm volatile("" : "+a"(a[g][s]));   // steer to AGPR
        }
    }

    // phase-0 xv dump (cols 0..127 == kq0, s 0..3), STATIC a-indices
    if (kq == 0) {
        #pragma unroll
        for (int g = 0; g < 2; ++g) {
            short* d = &xvb[0][(rg * 32 + g * 16 + l15) * XROWS + quad * 8];
            *(v8s*)(d +  0) = a[g][0];
            *(v8s*)(d + 32) = a[g][1];
            *(v8s*)(d + 64) = a[g][2];
            *(v8s*)(d + 96) = a[g][3];
        }
    }

    asm volatile("s_waitcnt lgkmcnt(0)" ::: "memory");
    asm volatile("s_waitcnt vmcnt(4)" ::: "memory");   // tile 0 done, 1 in flight
    __builtin_amdgcn_s_barrier();
    __builtin_amdgcn_sched_barrier(0);

    float acc[2][4];
    #pragma unroll
    for (int g = 0; g < 2; ++g)
        #pragma unroll
        for (int r = 0; r < 4; ++r) acc[g][r] = 0.f;

    for (int t = 0; t < 64; ++t) {
        // (1) issue tile t+2 (stays in flight across this round's barrier)
        if (t + 2 < 64) stage((t + 2) % 3, t + 2);

        // (2) dump next 128-col phase's xv from A regs (static indices)
        if ((t & 7) == 0 && t < 56) {
            const int ph = (t >> 3) + 1;          // 1..7
            if (kq == (ph >> 1)) {
                short* base = &xvb[ph & 1][0];
                if (ph & 1) {
                    #pragma unroll
                    for (int g = 0; g < 2; ++g) {
                        short* d = base + (rg * 32 + g * 16 + l15) * XROWS + quad * 8;
                        *(v8s*)(d +  0) = a[g][4];
                        *(v8s*)(d + 32) = a[g][5];
                        *(v8s*)(d + 64) = a[g][6];
                        *(v8s*)(d + 96) = a[g][7];
                    }
                } else {
                    #pragma unroll
                    for (int g = 0; g < 2; ++g) {
                        short* d = base + (rg * 32 + g * 16 + l15) * XROWS + quad * 8;
                        *(v8s*)(d +  0) = a[g][0];
                        *(v8s*)(d + 32) = a[g][1];
                        *(v8s*)(d + 64) = a[g][2];
                        *(v8s*)(d + 96) = a[g][3];
                    }
                }
            }
        }

        // (3) bias column (kq0 waves only -> added once per column)
        const float bb = (kq == 0) ? bvec[t * 16 + l15] : 0.f;

        // (4) MFMA: 8 ds_read_b128 (swizzled, bank-uniform) + 16 MFMA
        const char* tb = &tile[t % 3][0] + l15 * 2048;
        v4f cf[2];
        cf[0] = (v4f){0.f, 0.f, 0.f, 0.f};
        cf[1] = (v4f){0.f, 0.f, 0.f, 0.f};
        #pragma unroll
        for (int s = 0; s < 8; ++s) {
            const v8s bf = *(const v8s*)(tb + (((unsigned)(kq * 512 + s * 64 + quad * 16)) ^ (unsigned)xorc));
            cf[0] = MFMA16(a[0][s], bf, cf[0]);
            cf[1] = MFMA16(a[1][s], bf, cf[1]);
        }

        // (5) distributed dot with xv (C layout: row = quad*4+r, col = l15)
        const short* xp = &xvb[(t >> 3) & 1][0]
                        + (rg * 32 + quad * 4) * XROWS + (t & 7) * 16 + l15;
        #pragma unroll
        for (int g = 0; g < 2; ++g)
            #pragma unroll
            for (int r = 0; r < 4; ++r)
                acc[g][r] += (cf[g][r] + bb) * b2f(xp[(g * 16 + r) * XROWS]);

        // (6) end-of-round: counted vmcnt keeps tile t+2's DMA in flight
        asm volatile("s_waitcnt lgkmcnt(0)" ::: "memory");
        if (t + 2 < 64) asm volatile("s_waitcnt vmcnt(4)" ::: "memory");
        else            asm volatile("s_waitcnt vmcnt(0)" ::: "memory");
        __builtin_amdgcn_s_barrier();
        __builtin_amdgcn_sched_barrier(0);
    }

    // ---- reduce 16 l15-lanes (shfl), then 4 kq-waves (LDS), store ----
    #pragma unroll
    for (int g = 0; g < 2; ++g)
        #pragma unroll
        for (int r = 0; r < 4; ++r) {
            float v = acc[g][r];
            v += __shfl_xor(v, 1); v += __shfl_xor(v, 2);
            v += __shfl_xor(v, 4); v += __shfl_xor(v, 8);
            if (l15 == 0)
                yred[kq][rg * 32 + g * 16 + quad * 4 + r] = v;
        }
    __syncthreads();
    if (tid < 64)
        y[row_base + tid] = yred[0][tid] + yred[1][tid] + yred[2][tid]
                          + yred[3][tid] + cptr[0];
}

extern "C" void kernel_launch(void* const* d_in, const int* in_sizes, int n_in,
                              void* d_out, int out_size, void* d_ws, size_t ws_size,
                              hipStream_t stream)
{
    const float* x = (const float*)d_in[0];
    const float* Q = (const float*)d_in[1];
    const float* b = (const float*)d_in[2];
    const float* c = (const float*)d_in[3];
    float* y = (float*)d_out;
    char* qb = (char*)d_ws;   // 2 MB bf16 tiled/swizzled Q image

    cvt_kernel<<<dim3(512), dim3(256), 0, stream>>>(Q, qb);
    quad_kernel<<<dim3(256), dim3(512), 0, stream>>>(x, qb, b, c, y);
}